// Round 7
// baseline (32.347 us; speedup 1.0000x reference)
//
#include <hip/hip_runtime.h>

// TrafficNetworkDQN fused forward via fp16 MFMA (gfx950).
//
// All layers computed TRANSPOSED:  Act_out[n, m] = W^T[n,k] @ Act_in[k, m] + b[n]
// with positions m on the MFMA *N* dimension: the C/D fragment layout
// (col = lane&15 = m, row = 4*(lane>>4)+reg = n) equals the next layer's
// B fragment layout, so layer transitions are in-lane relu+cvt only.
//
// R7: batch-prefetch + full unroll. Diagnosis: R5/R6 eliminated MFMA issue,
// VALU issue, prologue cost and chain-ILP as the bound; residual stall is
// per-iteration exposed load latency (loads -> vmcnt stall -> chain, x4).
// Fix: per 4-tile group, issue ALL lf/ss loads back-to-back (one latency
// exposure), then all emb ds_reads, then 4 independent fully-unrolled MFMA
// chains in one basic block for scheduler interleaving.

#define BL_TOTAL (4096 * 256)

// d_ws layout: 12 half4 frags at f*512 + lane*8, then 9 float4 biases at
// 7680 + b*1024 + lane*16.
#define WS_FRAG(ws, f)  (reinterpret_cast<half4*>((char*)(ws) + (f) * 512))
#define WS_BIAS(ws, b)  (reinterpret_cast<floatx4*>((char*)(ws) + 7680 + (b) * 1024))
#define WS_FRAG_C(ws, f) (reinterpret_cast<const half4*>((const char*)(ws) + (f) * 512))
#define WS_BIAS_C(ws, b) (reinterpret_cast<const floatx4*>((const char*)(ws) + 7680 + (b) * 1024))

typedef _Float16 half4   __attribute__((ext_vector_type(4)));
typedef __fp16   fp16x2  __attribute__((ext_vector_type(2)));
typedef float    floatx4 __attribute__((ext_vector_type(4)));

#define MFMA16(A, B, C) __builtin_amdgcn_mfma_f32_16x16x16f16((A), (B), (C), 0, 0, 0)

static __device__ __forceinline__ half4 relu_pack(floatx4 c) {
    float a0 = fmaxf(c[0], 0.0f), a1 = fmaxf(c[1], 0.0f);
    float a2 = fmaxf(c[2], 0.0f), a3 = fmaxf(c[3], 0.0f);
    fp16x2 lo = __builtin_amdgcn_cvt_pkrtz(a0, a1);
    fp16x2 hi = __builtin_amdgcn_cvt_pkrtz(a2, a3);
    half4 r;
    r[0] = (_Float16)lo[0]; r[1] = (_Float16)lo[1];
    r[2] = (_Float16)hi[0]; r[3] = (_Float16)hi[1];
    return r;
}

static __device__ __forceinline__ half4 pack4_rne(float a, float b, float c, float d) {
    half4 r; r[0] = (_Float16)a; r[1] = (_Float16)b; r[2] = (_Float16)c; r[3] = (_Float16)d;
    return r;
}

// ---------------- setup kernel: 1 block x 64 threads ----------------
__global__ void dqn_setup(
    const float* __restrict__ le_w1, const float* __restrict__ le_b1,
    const float* __restrict__ le_w2, const float* __restrict__ le_b2,
    const float* __restrict__ ls_w1, const float* __restrict__ ls_b1,
    const float* __restrict__ ls_w2, const float* __restrict__ ls_b2,
    const float* __restrict__ ls_w3, const float* __restrict__ ls_b3,
    const float* __restrict__ as_w1, const float* __restrict__ as_b1,
    const float* __restrict__ as_w2, const float* __restrict__ as_b2,
    const float* __restrict__ as_w3, const float* __restrict__ as_b3,
    void* __restrict__ ws)
{
    const int lane = threadIdx.x;   // 0..63
    const int m16  = lane & 15;
    const int g    = lane >> 4;
    const int k0   = g * 4;

    WS_FRAG(ws, 0)[lane] = pack4_rne(
        (k0 + 0 < 5) ? le_w1[(k0 + 0) * 16 + m16] : 0.0f,
        (k0 + 1 < 5) ? le_w1[(k0 + 1) * 16 + m16] : 0.0f,
        (k0 + 2 < 5) ? le_w1[(k0 + 2) * 16 + m16] : 0.0f,
        (k0 + 3 < 5) ? le_w1[(k0 + 3) * 16 + m16] : 0.0f);
    WS_FRAG(ws, 1)[lane] = pack4_rne(
        (m16 < 8) ? le_w2[(k0 + 0) * 8 + m16] : 0.0f,
        (m16 < 8) ? le_w2[(k0 + 1) * 8 + m16] : 0.0f,
        (m16 < 8) ? le_w2[(k0 + 2) * 8 + m16] : 0.0f,
        (m16 < 8) ? le_w2[(k0 + 3) * 8 + m16] : 0.0f);
    WS_FRAG(ws, 2)[lane] = pack4_rne(ls_w1[(k0+0)*32 + m16],      ls_w1[(k0+1)*32 + m16],
                                     ls_w1[(k0+2)*32 + m16],      ls_w1[(k0+3)*32 + m16]);
    WS_FRAG(ws, 3)[lane] = pack4_rne(ls_w1[(k0+0)*32 + 16 + m16], ls_w1[(k0+1)*32 + 16 + m16],
                                     ls_w1[(k0+2)*32 + 16 + m16], ls_w1[(k0+3)*32 + 16 + m16]);
    WS_FRAG(ws, 4)[lane] = pack4_rne(as_w1[(k0+0)*32 + m16],      as_w1[(k0+1)*32 + m16],
                                     as_w1[(k0+2)*32 + m16],      as_w1[(k0+3)*32 + m16]);
    WS_FRAG(ws, 5)[lane] = pack4_rne(as_w1[(k0+0)*32 + 16 + m16], as_w1[(k0+1)*32 + 16 + m16],
                                     as_w1[(k0+2)*32 + 16 + m16], as_w1[(k0+3)*32 + 16 + m16]);
    WS_FRAG(ws, 6)[lane] = pack4_rne(ls_w2[(k0+0)*16 + m16],      ls_w2[(k0+1)*16 + m16],
                                     ls_w2[(k0+2)*16 + m16],      ls_w2[(k0+3)*16 + m16]);
    WS_FRAG(ws, 7)[lane] = pack4_rne(ls_w2[(16+k0+0)*16 + m16],   ls_w2[(16+k0+1)*16 + m16],
                                     ls_w2[(16+k0+2)*16 + m16],   ls_w2[(16+k0+3)*16 + m16]);
    WS_FRAG(ws, 8)[lane] = pack4_rne(as_w2[(k0+0)*16 + m16],      as_w2[(k0+1)*16 + m16],
                                     as_w2[(k0+2)*16 + m16],      as_w2[(k0+3)*16 + m16]);
    WS_FRAG(ws, 9)[lane] = pack4_rne(as_w2[(16+k0+0)*16 + m16],   as_w2[(16+k0+1)*16 + m16],
                                     as_w2[(16+k0+2)*16 + m16],   as_w2[(16+k0+3)*16 + m16]);
    WS_FRAG(ws, 10)[lane] = pack4_rne(
        (m16 == 0) ? ls_w3[k0 + 0] : 0.0f,
        (m16 == 0) ? ls_w3[k0 + 1] : 0.0f,
        (m16 == 0) ? ls_w3[k0 + 2] : 0.0f,
        (m16 == 0) ? ls_w3[k0 + 3] : 0.0f);
    WS_FRAG(ws, 11)[lane] = pack4_rne(
        (m16 == 1) ? as_w3[(k0+0)*2] : ((m16 == 2) ? as_w3[(k0+0)*2 + 1] : 0.0f),
        (m16 == 1) ? as_w3[(k0+1)*2] : ((m16 == 2) ? as_w3[(k0+1)*2 + 1] : 0.0f),
        (m16 == 1) ? as_w3[(k0+2)*2] : ((m16 == 2) ? as_w3[(k0+2)*2 + 1] : 0.0f),
        (m16 == 1) ? as_w3[(k0+3)*2] : ((m16 == 2) ? as_w3[(k0+3)*2 + 1] : 0.0f));

    const int n0 = 4 * g;
    floatx4 bias1, bias2, bias3_0, bias3_1, bias3_2, bias3_3, bias4ls, bias4as, bias5;
    #pragma unroll
    for (int r = 0; r < 4; ++r) {
        bias1[r]   = le_b1[n0 + r];
        bias2[r]   = (n0 + r < 8) ? le_b2[n0 + r] : 0.0f;
        bias3_0[r] = ls_b1[n0 + r];
        bias3_1[r] = ls_b1[16 + n0 + r];
        bias3_2[r] = as_b1[n0 + r];
        bias3_3[r] = as_b1[16 + n0 + r];
        bias4ls[r] = ls_b2[n0 + r];
        bias4as[r] = as_b2[n0 + r];
        bias5[r]   = 0.0f;
    }
    if (g == 0) { bias5[0] = ls_b3[0]; bias5[1] = as_b3[0]; bias5[2] = as_b3[1]; }
    WS_BIAS(ws, 0)[lane] = bias1;
    WS_BIAS(ws, 1)[lane] = bias2;
    WS_BIAS(ws, 2)[lane] = bias3_0;
    WS_BIAS(ws, 3)[lane] = bias3_1;
    WS_BIAS(ws, 4)[lane] = bias3_2;
    WS_BIAS(ws, 5)[lane] = bias3_3;
    WS_BIAS(ws, 6)[lane] = bias4ls;
    WS_BIAS(ws, 7)[lane] = bias4as;
    WS_BIAS(ws, 8)[lane] = bias5;
}

// ---------------- main kernel ----------------
__global__ __launch_bounds__(256, 4) void dqn_mfma(
    const float* __restrict__ lf,    // [BL,5]
    const int*   __restrict__ ss,    // [BL]
    const float* __restrict__ emb,   // 8x8
    const void*  __restrict__ ws,    // packed fragments from dqn_setup
    float* __restrict__ out)         // [BL] scores, then [BL,2] action values
{
    const int lane = threadIdx.x & 63;
    const int wave = threadIdx.x >> 6;
    const int m16  = lane & 15;
    const int g    = lane >> 4;

    // ---- stage emb table to LDS as fp16 [8][8] ----
    __shared__ _Float16 embLDS[64];
    if (threadIdx.x < 64) embLDS[threadIdx.x] = (_Float16)emb[threadIdx.x];
    __syncthreads();

    // ---- coalesced fragment loads (L2-hot broadcast) ----
    const half4 a1    = WS_FRAG_C(ws, 0)[lane];
    const half4 a2    = WS_FRAG_C(ws, 1)[lane];
    const half4 a3_0  = WS_FRAG_C(ws, 2)[lane];
    const half4 a3_1  = WS_FRAG_C(ws, 3)[lane];
    const half4 a3_2  = WS_FRAG_C(ws, 4)[lane];
    const half4 a3_3  = WS_FRAG_C(ws, 5)[lane];
    const half4 a4ls0 = WS_FRAG_C(ws, 6)[lane];
    const half4 a4ls1 = WS_FRAG_C(ws, 7)[lane];
    const half4 a4as0 = WS_FRAG_C(ws, 8)[lane];
    const half4 a4as1 = WS_FRAG_C(ws, 9)[lane];
    const half4 a5a   = WS_FRAG_C(ws, 10)[lane];
    const half4 a5b   = WS_FRAG_C(ws, 11)[lane];
    const floatx4 bias1   = WS_BIAS_C(ws, 0)[lane];
    const floatx4 bias2   = WS_BIAS_C(ws, 1)[lane];
    const floatx4 bias3_0 = WS_BIAS_C(ws, 2)[lane];
    const floatx4 bias3_1 = WS_BIAS_C(ws, 3)[lane];
    const floatx4 bias3_2 = WS_BIAS_C(ws, 4)[lane];
    const floatx4 bias3_3 = WS_BIAS_C(ws, 5)[lane];
    const floatx4 bias4ls = WS_BIAS_C(ws, 6)[lane];
    const floatx4 bias4as = WS_BIAS_C(ws, 7)[lane];
    const floatx4 bias5   = WS_BIAS_C(ws, 8)[lane];

    const int tile0 = blockIdx.x * 32 + wave * 8;
    float* __restrict__ out2 = out + BL_TOTAL;

    for (int h = 0; h < 2; ++h) {
        const int tb = tile0 + h * 4;

        // ---- batch prefetch: all 12 VMEM issued before any use ----
        float ax[4][4];
        int   sv[4];
        #pragma unroll
        for (int i = 0; i < 4; ++i) {
            const int pos = (tb + i) * 16 + m16;
            float v0 = 0.0f, v1 = 0.0f, v2 = 0.0f, v3 = 0.0f;
            if (g == 0) {
                v0 = lf[pos * 5 + 0]; v1 = lf[pos * 5 + 1];
                v2 = lf[pos * 5 + 2]; v3 = lf[pos * 5 + 3];
            } else if (g == 1) {
                v0 = lf[pos * 5 + 4];
            }
            ax[i][0] = v0; ax[i][1] = v1; ax[i][2] = v2; ax[i][3] = v3;
            sv[i] = ss[pos];
        }
        half4 ev[4];
        #pragma unroll
        for (int i = 0; i < 4; ++i)
            ev[i] = *reinterpret_cast<const half4*>(&embLDS[sv[i] * 8 + (g & 1) * 4]);
        half4 b1[4];
        #pragma unroll
        for (int i = 0; i < 4; ++i)
            b1[i] = pack4_rne(ax[i][0], ax[i][1], ax[i][2], ax[i][3]);

        // ---- 4 independent chains, one basic block ----
        #pragma unroll
        for (int i = 0; i < 4; ++i) {
            const int pos = (tb + i) * 16 + m16;

            floatx4 c1 = MFMA16(a1, b1[i], bias1);
            half4 h1 = relu_pack(c1);

            floatx4 c2 = MFMA16(a2, h1, bias2);
            half4 b3 = relu_pack(c2);
            if (g >= 2) b3 = ev[i];

            floatx4 c30 = MFMA16(a3_0, b3, bias3_0);
            floatx4 c31 = MFMA16(a3_1, b3, bias3_1);
            floatx4 c32 = MFMA16(a3_2, b3, bias3_2);
            floatx4 c33 = MFMA16(a3_3, b3, bias3_3);
            half4 p0 = relu_pack(c30), p1 = relu_pack(c31);
            half4 p2 = relu_pack(c32), p3 = relu_pack(c33);

            floatx4 cls = MFMA16(a4ls1, p1, MFMA16(a4ls0, p0, bias4ls));
            floatx4 cas = MFMA16(a4as1, p3, MFMA16(a4as0, p2, bias4as));
            half4 hls = relu_pack(cls), has = relu_pack(cas);

            floatx4 c5 = MFMA16(a5b, has, MFMA16(a5a, hls, bias5));
            if (g == 0) {
                out[pos] = c5[0];
                reinterpret_cast<float2*>(out2)[pos] = make_float2(c5[1], c5[2]);
            }
        }
    }
}

extern "C" void kernel_launch(void* const* d_in, const int* in_sizes, int n_in,
                              void* d_out, int out_size, void* d_ws, size_t ws_size,
                              hipStream_t stream) {
    const float* lf    = (const float*)d_in[0];
    const int*   ss    = (const int*)  d_in[1];
    const float* le_w1 = (const float*)d_in[2];
    const float* le_b1 = (const float*)d_in[3];
    const float* le_w2 = (const float*)d_in[4];
    const float* le_b2 = (const float*)d_in[5];
    const float* emb   = (const float*)d_in[6];
    const float* ls_w1 = (const float*)d_in[7];
    const float* ls_b1 = (const float*)d_in[8];
    const float* ls_w2 = (const float*)d_in[9];
    const float* ls_b2 = (const float*)d_in[10];
    const float* ls_w3 = (const float*)d_in[11];
    const float* ls_b3 = (const float*)d_in[12];
    const float* as_w1 = (const float*)d_in[13];
    const float* as_b1 = (const float*)d_in[14];
    const float* as_w2 = (const float*)d_in[15];
    const float* as_b2 = (const float*)d_in[16];
    const float* as_w3 = (const float*)d_in[17];
    const float* as_b3 = (const float*)d_in[18];
    float* out = (float*)d_out;

    dqn_setup<<<1, 64, 0, stream>>>(
        le_w1, le_b1, le_w2, le_b2,
        ls_w1, ls_b1, ls_w2, ls_b2, ls_w3, ls_b3,
        as_w1, as_b1, as_w2, as_b2, as_w3, as_b3, d_ws);

    // 2048 blocks x 4 waves x 8 tiles x 16 positions = 1,048,576
    dqn_mfma<<<2048, 256, 0, stream>>>(lf, ss, emb, d_ws, out);
}

// Round 8
// 29.729 us; speedup vs baseline: 1.0881x; 1.0881x over previous
//
#include <hip/hip_runtime.h>

// TrafficNetworkDQN fused forward via fp16 MFMA (gfx950).
//
// All layers computed TRANSPOSED:  Act_out[n, m] = W^T[n,k] @ Act_in[k, m] + b[n]
// with positions m on the MFMA *N* dimension: the C/D fragment layout
// (col = lane&15 = m, row = 4*(lane>>4)+reg = n) equals the K=16 B fragment
// layout (k = 4*(lane>>4)+j), so layer transitions are in-lane relu+cvt only.
// HW-verified by R3's pass.
//
// R8: shorten the serial chain with K=32 MFMAs (gfx950 mfma_f32_16x16x32_f16).
// The K=32 B fragment is the two-half extension (j>=4 -> k+16), i.e. the
// in-lane CONCAT of two K=16 C/D fragments -- so L4 (K=32) and L5 (K=32:
// hls||has) become single MFMAs. 12 MFMAs/7-deep -> 9 MFMAs/5-deep per tile.
// Diagnosis: R5-R7 showed ILP x occupancy is register-conserved; the only
// free lever is chain depth. Base = R5 (best known, 29.2us, 2-way ILP).

#define BL_TOTAL (4096 * 256)

typedef _Float16 half4   __attribute__((ext_vector_type(4)));
typedef _Float16 half8   __attribute__((ext_vector_type(8)));
typedef __fp16   fp16x2  __attribute__((ext_vector_type(2)));
typedef float    floatx4 __attribute__((ext_vector_type(4)));

#define MFMA16(A, B, C) __builtin_amdgcn_mfma_f32_16x16x16f16((A), (B), (C), 0, 0, 0)
#define MFMA32(A, B, C) __builtin_amdgcn_mfma_f32_16x16x32_f16((A), (B), (C), 0, 0, 0)

static __device__ __forceinline__ half4 relu_pack(floatx4 c) {
    float a0 = fmaxf(c[0], 0.0f), a1 = fmaxf(c[1], 0.0f);
    float a2 = fmaxf(c[2], 0.0f), a3 = fmaxf(c[3], 0.0f);
    fp16x2 lo = __builtin_amdgcn_cvt_pkrtz(a0, a1);
    fp16x2 hi = __builtin_amdgcn_cvt_pkrtz(a2, a3);
    half4 r;
    r[0] = (_Float16)lo[0]; r[1] = (_Float16)lo[1];
    r[2] = (_Float16)hi[0]; r[3] = (_Float16)hi[1];
    return r;
}

static __device__ __forceinline__ half4 pack4_rne(float a, float b, float c, float d) {
    half4 r; r[0] = (_Float16)a; r[1] = (_Float16)b; r[2] = (_Float16)c; r[3] = (_Float16)d;
    return r;
}

static __device__ __forceinline__ half8 cat8(half4 x, half4 y) {
    half8 r;
    r[0] = x[0]; r[1] = x[1]; r[2] = x[2]; r[3] = x[3];
    r[4] = y[0]; r[5] = y[1]; r[6] = y[2]; r[7] = y[3];
    return r;
}

__global__ __launch_bounds__(256, 4) void dqn_mfma(
    const float* __restrict__ lf,    // [BL,5]
    const int*   __restrict__ ss,    // [BL]
    const float* __restrict__ le_w1, const float* __restrict__ le_b1,   // 5x16, 16
    const float* __restrict__ le_w2, const float* __restrict__ le_b2,   // 16x8, 8
    const float* __restrict__ emb,                                      // 8x8
    const float* __restrict__ ls_w1, const float* __restrict__ ls_b1,   // 16x32, 32
    const float* __restrict__ ls_w2, const float* __restrict__ ls_b2,   // 32x16, 16
    const float* __restrict__ ls_w3, const float* __restrict__ ls_b3,   // 16x1, 1
    const float* __restrict__ as_w1, const float* __restrict__ as_b1,   // 16x32, 32
    const float* __restrict__ as_w2, const float* __restrict__ as_b2,   // 32x16, 16
    const float* __restrict__ as_w3, const float* __restrict__ as_b3,   // 16x2, 2
    float* __restrict__ out)         // [BL] scores, then [BL,2] action values
{
    const int lane = threadIdx.x & 63;
    const int wave = threadIdx.x >> 6;
    const int m16  = lane & 15;
    const int g    = lane >> 4;
    const int k0   = g * 4;

    // ---- stage emb table to LDS as fp16 [8][8] ----
    __shared__ _Float16 embLDS[64];
    if (threadIdx.x < 64) embLDS[threadIdx.x] = (_Float16)emb[threadIdx.x];
    __syncthreads();

    // ---- A fragments (K=16): A[n=m16][k=k0+j] = W[k][n] ----
    half4 a1 = pack4_rne(
        (k0 + 0 < 5) ? le_w1[(k0 + 0) * 16 + m16] : 0.0f,
        (k0 + 1 < 5) ? le_w1[(k0 + 1) * 16 + m16] : 0.0f,
        (k0 + 2 < 5) ? le_w1[(k0 + 2) * 16 + m16] : 0.0f,
        (k0 + 3 < 5) ? le_w1[(k0 + 3) * 16 + m16] : 0.0f);
    half4 a2 = pack4_rne(
        (m16 < 8) ? le_w2[(k0 + 0) * 8 + m16] : 0.0f,
        (m16 < 8) ? le_w2[(k0 + 1) * 8 + m16] : 0.0f,
        (m16 < 8) ? le_w2[(k0 + 2) * 8 + m16] : 0.0f,
        (m16 < 8) ? le_w2[(k0 + 3) * 8 + m16] : 0.0f);
    half4 a3_0 = pack4_rne(ls_w1[(k0+0)*32 + m16],      ls_w1[(k0+1)*32 + m16],
                           ls_w1[(k0+2)*32 + m16],      ls_w1[(k0+3)*32 + m16]);
    half4 a3_1 = pack4_rne(ls_w1[(k0+0)*32 + 16 + m16], ls_w1[(k0+1)*32 + 16 + m16],
                           ls_w1[(k0+2)*32 + 16 + m16], ls_w1[(k0+3)*32 + 16 + m16]);
    half4 a3_2 = pack4_rne(as_w1[(k0+0)*32 + m16],      as_w1[(k0+1)*32 + m16],
                           as_w1[(k0+2)*32 + m16],      as_w1[(k0+3)*32 + m16]);
    half4 a3_3 = pack4_rne(as_w1[(k0+0)*32 + 16 + m16], as_w1[(k0+1)*32 + 16 + m16],
                           as_w1[(k0+2)*32 + 16 + m16], as_w1[(k0+3)*32 + 16 + m16]);

    // ---- A fragments (K=32): j<4 -> k=k0+j, j>=4 -> k=16+k0+(j-4) ----
    half8 a4ls = cat8(
        pack4_rne(ls_w2[(k0+0)*16 + m16],    ls_w2[(k0+1)*16 + m16],
                  ls_w2[(k0+2)*16 + m16],    ls_w2[(k0+3)*16 + m16]),
        pack4_rne(ls_w2[(16+k0+0)*16 + m16], ls_w2[(16+k0+1)*16 + m16],
                  ls_w2[(16+k0+2)*16 + m16], ls_w2[(16+k0+3)*16 + m16]));
    half8 a4as = cat8(
        pack4_rne(as_w2[(k0+0)*16 + m16],    as_w2[(k0+1)*16 + m16],
                  as_w2[(k0+2)*16 + m16],    as_w2[(k0+3)*16 + m16]),
        pack4_rne(as_w2[(16+k0+0)*16 + m16], as_w2[(16+k0+1)*16 + m16],
                  as_w2[(16+k0+2)*16 + m16], as_w2[(16+k0+3)*16 + m16]));
    // L5: k<16 (hls) feeds n=0 via ls_w3; k>=16 (has) feeds n=1,2 via as_w3
    half8 a5 = cat8(
        pack4_rne(
            (m16 == 0) ? ls_w3[k0 + 0] : 0.0f,
            (m16 == 0) ? ls_w3[k0 + 1] : 0.0f,
            (m16 == 0) ? ls_w3[k0 + 2] : 0.0f,
            (m16 == 0) ? ls_w3[k0 + 3] : 0.0f),
        pack4_rne(
            (m16 == 1) ? as_w3[(k0+0)*2] : ((m16 == 2) ? as_w3[(k0+0)*2 + 1] : 0.0f),
            (m16 == 1) ? as_w3[(k0+1)*2] : ((m16 == 2) ? as_w3[(k0+1)*2 + 1] : 0.0f),
            (m16 == 1) ? as_w3[(k0+2)*2] : ((m16 == 2) ? as_w3[(k0+2)*2 + 1] : 0.0f),
            (m16 == 1) ? as_w3[(k0+3)*2] : ((m16 == 2) ? as_w3[(k0+3)*2 + 1] : 0.0f)));

    // ---- bias fragments: C-in, reg r -> n = 4*g + r ----
    const int n0 = 4 * g;
    floatx4 bias1, bias2, bias3_0, bias3_1, bias3_2, bias3_3, bias4ls, bias4as, bias5;
    #pragma unroll
    for (int r = 0; r < 4; ++r) {
        bias1[r]   = le_b1[n0 + r];
        bias2[r]   = (n0 + r < 8) ? le_b2[n0 + r] : 0.0f;
        bias3_0[r] = ls_b1[n0 + r];
        bias3_1[r] = ls_b1[16 + n0 + r];
        bias3_2[r] = as_b1[n0 + r];
        bias3_3[r] = as_b1[16 + n0 + r];
        bias4ls[r] = ls_b2[n0 + r];
        bias4as[r] = as_b2[n0 + r];
        bias5[r]   = 0.0f;
    }
    if (g == 0) { bias5[0] = ls_b3[0]; bias5[1] = as_b3[0]; bias5[2] = as_b3[1]; }

    // ---- main loop: 8 tiles per wave, 2 independent chains per iteration ----
    const int tile0 = blockIdx.x * 32 + wave * 8;
    float* __restrict__ out2 = out + BL_TOTAL;

    for (int t = 0; t < 8; t += 2) {
        const int posA = (tile0 + t) * 16 + m16;
        const int posB = posA + 16;

        float ax0 = 0.0f, ax1 = 0.0f, ax2 = 0.0f, ax3 = 0.0f;
        float bx0 = 0.0f, bx1 = 0.0f, bx2 = 0.0f, bx3 = 0.0f;
        if (g == 0) {
            ax0 = lf[posA * 5 + 0]; ax1 = lf[posA * 5 + 1];
            ax2 = lf[posA * 5 + 2]; ax3 = lf[posA * 5 + 3];
            bx0 = lf[posB * 5 + 0]; bx1 = lf[posB * 5 + 1];
            bx2 = lf[posB * 5 + 2]; bx3 = lf[posB * 5 + 3];
        } else if (g == 1) {
            ax0 = lf[posA * 5 + 4];
            bx0 = lf[posB * 5 + 4];
        }
        const int sA = ss[posA];
        const int sB = ss[posB];
        half4 evA = *reinterpret_cast<const half4*>(&embLDS[sA * 8 + (g & 1) * 4]);
        half4 evB = *reinterpret_cast<const half4*>(&embLDS[sB * 8 + (g & 1) * 4]);

        half4 b1A = pack4_rne(ax0, ax1, ax2, ax3);
        half4 b1B = pack4_rne(bx0, bx1, bx2, bx3);

        // L1: 5->16
        floatx4 c1A = MFMA16(a1, b1A, bias1);
        floatx4 c1B = MFMA16(a1, b1B, bias1);
        half4 h1A = relu_pack(c1A);
        half4 h1B = relu_pack(c1B);

        // L2: 16->8
        floatx4 c2A = MFMA16(a2, h1A, bias2);
        floatx4 c2B = MFMA16(a2, h1B, bias2);
        half4 b3A = relu_pack(c2A);
        half4 b3B = relu_pack(c2B);
        if (g >= 2) { b3A = evA; b3B = evB; }

        // L3: 16->64 (both heads' W1 stacked on n)
        floatx4 c30A = MFMA16(a3_0, b3A, bias3_0);
        floatx4 c30B = MFMA16(a3_0, b3B, bias3_0);
        floatx4 c31A = MFMA16(a3_1, b3A, bias3_1);
        floatx4 c31B = MFMA16(a3_1, b3B, bias3_1);
        floatx4 c32A = MFMA16(a3_2, b3A, bias3_2);
        floatx4 c32B = MFMA16(a3_2, b3B, bias3_2);
        floatx4 c33A = MFMA16(a3_3, b3A, bias3_3);
        floatx4 c33B = MFMA16(a3_3, b3B, bias3_3);
        half4 p0A = relu_pack(c30A), p1A = relu_pack(c31A);
        half4 p2A = relu_pack(c32A), p3A = relu_pack(c33A);
        half4 p0B = relu_pack(c30B), p1B = relu_pack(c31B);
        half4 p2B = relu_pack(c32B), p3B = relu_pack(c33B);

        // L4: 32->16 per head, single K=32 MFMA each
        floatx4 clsA = MFMA32(a4ls, cat8(p0A, p1A), bias4ls);
        floatx4 clsB = MFMA32(a4ls, cat8(p0B, p1B), bias4ls);
        floatx4 casA = MFMA32(a4as, cat8(p2A, p3A), bias4as);
        floatx4 casB = MFMA32(a4as, cat8(p2B, p3B), bias4as);
        half4 hlsA = relu_pack(clsA), hasA = relu_pack(casA);
        half4 hlsB = relu_pack(clsB), hasB = relu_pack(casB);

        // L5: 32->3 (hls||has), single K=32 MFMA
        floatx4 c5A = MFMA32(a5, cat8(hlsA, hasA), bias5);
        floatx4 c5B = MFMA32(a5, cat8(hlsB, hasB), bias5);

        // lane group 0 holds n=0 (score), n=1 (av0), n=2 (av1) for position m16
        if (g == 0) {
            out[posA] = c5A[0];
            out[posB] = c5B[0];
            reinterpret_cast<float2*>(out2)[posA] = make_float2(c5A[1], c5A[2]);
            reinterpret_cast<float2*>(out2)[posB] = make_float2(c5B[1], c5B[2]);
        }
    }
}

extern "C" void kernel_launch(void* const* d_in, const int* in_sizes, int n_in,
                              void* d_out, int out_size, void* d_ws, size_t ws_size,
                              hipStream_t stream) {
    const float* lf    = (const float*)d_in[0];
    const int*   ss    = (const int*)  d_in[1];
    const float* le_w1 = (const float*)d_in[2];
    const float* le_b1 = (const float*)d_in[3];
    const float* le_w2 = (const float*)d_in[4];
    const float* le_b2 = (const float*)d_in[5];
    const float* emb   = (const float*)d_in[6];
    const float* ls_w1 = (const float*)d_in[7];
    const float* ls_b1 = (const float*)d_in[8];
    const float* ls_w2 = (const float*)d_in[9];
    const float* ls_b2 = (const float*)d_in[10];
    const float* ls_w3 = (const float*)d_in[11];
    const float* ls_b3 = (const float*)d_in[12];
    const float* as_w1 = (const float*)d_in[13];
    const float* as_b1 = (const float*)d_in[14];
    const float* as_w2 = (const float*)d_in[15];
    const float* as_b2 = (const float*)d_in[16];
    const float* as_w3 = (const float*)d_in[17];
    const float* as_b3 = (const float*)d_in[18];
    float* out = (float*)d_out;

    // 2048 blocks x 4 waves x 8 tiles x 16 positions = 1,048,576
    dqn_mfma<<<2048, 256, 0, stream>>>(
        lf, ss, le_w1, le_b1, le_w2, le_b2, emb,
        ls_w1, ls_b1, ls_w2, ls_b2, ls_w3, ls_b3,
        as_w1, as_b1, as_w2, as_b2, as_w3, as_b3,
        out);
}

// Round 9
// 26.111 us; speedup vs baseline: 1.2388x; 1.1386x over previous
//
#include <hip/hip_runtime.h>

// TrafficNetworkDQN fused forward via fp16 MFMA (gfx950).
//
// All layers computed TRANSPOSED:  Act_out[n, m] = W^T[n,k] @ Act_in[k, m] + b[n]
// with positions m on the MFMA *N* dimension: the C/D fragment layout
// (col = lane&15 = m, row = 4*(lane>>4)+reg = n) equals the K=16 B fragment
// layout (k = 4*(lane>>4)+j); K=32 B frag = in-lane concat of two K=16 C/D
// frags (j>=4 -> k+16). Both HW-verified (R3, R8 passes).
//
// R9: cooperative prologue. Diagnosis: ~half of per-wave VALU issue is the
// fragment-construction prologue (~800 instrs: scattered loads, cvt, selects),
// re-executed by all 4 waves/block. Fix: each wave builds ~1/4 of the
// fragment/bias rows into LDS (wave-uniform, no divergence), barrier, then
// all lanes read back 21 rows via ds_read_b64/b128. Loop = R8's K=32 body.

#define BL_TOTAL (4096 * 256)

typedef _Float16 half4   __attribute__((ext_vector_type(4)));
typedef _Float16 half8   __attribute__((ext_vector_type(8)));
typedef __fp16   fp16x2  __attribute__((ext_vector_type(2)));
typedef float    floatx4 __attribute__((ext_vector_type(4)));

#define MFMA16(A, B, C) __builtin_amdgcn_mfma_f32_16x16x16f16((A), (B), (C), 0, 0, 0)
#define MFMA32(A, B, C) __builtin_amdgcn_mfma_f32_16x16x32_f16((A), (B), (C), 0, 0, 0)

static __device__ __forceinline__ half4 relu_pack(floatx4 c) {
    float a0 = fmaxf(c[0], 0.0f), a1 = fmaxf(c[1], 0.0f);
    float a2 = fmaxf(c[2], 0.0f), a3 = fmaxf(c[3], 0.0f);
    fp16x2 lo = __builtin_amdgcn_cvt_pkrtz(a0, a1);
    fp16x2 hi = __builtin_amdgcn_cvt_pkrtz(a2, a3);
    half4 r;
    r[0] = (_Float16)lo[0]; r[1] = (_Float16)lo[1];
    r[2] = (_Float16)hi[0]; r[3] = (_Float16)hi[1];
    return r;
}

static __device__ __forceinline__ half4 pack4_rne(float a, float b, float c, float d) {
    half4 r; r[0] = (_Float16)a; r[1] = (_Float16)b; r[2] = (_Float16)c; r[3] = (_Float16)d;
    return r;
}

static __device__ __forceinline__ half8 cat8(half4 x, half4 y) {
    half8 r;
    r[0] = x[0]; r[1] = x[1]; r[2] = x[2]; r[3] = x[3];
    r[4] = y[0]; r[5] = y[1]; r[6] = y[2]; r[7] = y[3];
    return r;
}

__global__ __launch_bounds__(256, 4) void dqn_mfma(
    const float* __restrict__ lf,    // [BL,5]
    const int*   __restrict__ ss,    // [BL]
    const float* __restrict__ le_w1, const float* __restrict__ le_b1,   // 5x16, 16
    const float* __restrict__ le_w2, const float* __restrict__ le_b2,   // 16x8, 8
    const float* __restrict__ emb,                                      // 8x8
    const float* __restrict__ ls_w1, const float* __restrict__ ls_b1,   // 16x32, 32
    const float* __restrict__ ls_w2, const float* __restrict__ ls_b2,   // 32x16, 16
    const float* __restrict__ ls_w3, const float* __restrict__ ls_b3,   // 16x1, 1
    const float* __restrict__ as_w1, const float* __restrict__ as_b1,   // 16x32, 32
    const float* __restrict__ as_w2, const float* __restrict__ as_b2,   // 32x16, 16
    const float* __restrict__ as_w3, const float* __restrict__ as_b3,   // 16x2, 2
    float* __restrict__ out)         // [BL] scores, then [BL,2] action values
{
    const int lane = threadIdx.x & 63;
    const int wave = threadIdx.x >> 6;
    const int m16  = lane & 15;
    const int g    = lane >> 4;
    const int k0   = g * 4;

    // LDS: 6 half4 frag rows + 3 half8 frag rows + 9 float4 bias rows + emb
    __shared__ half4    f4LDS[6][64];    // a1, a2, a3_0, a3_1, a3_2, a3_3
    __shared__ half8    f8LDS[3][64];    // a4ls, a4as, a5
    __shared__ floatx4  bLDS[9][64];     // bias1,2,3_0,3_1,3_2,3_3,4ls,4as,5
    __shared__ _Float16 embLDS[64];

    // ---- cooperative construction: each wave builds ~1/4 of the rows ----
    if (wave == 0) {
        f4LDS[0][lane] = pack4_rne(
            (k0 + 0 < 5) ? le_w1[(k0 + 0) * 16 + m16] : 0.0f,
            (k0 + 1 < 5) ? le_w1[(k0 + 1) * 16 + m16] : 0.0f,
            (k0 + 2 < 5) ? le_w1[(k0 + 2) * 16 + m16] : 0.0f,
            (k0 + 3 < 5) ? le_w1[(k0 + 3) * 16 + m16] : 0.0f);
        f4LDS[4][lane] = pack4_rne(as_w1[(k0+0)*32 + m16],      as_w1[(k0+1)*32 + m16],
                                   as_w1[(k0+2)*32 + m16],      as_w1[(k0+3)*32 + m16]);
        floatx4 b1, b3_2, b5;
        #pragma unroll
        for (int r = 0; r < 4; ++r) {
            b1[r]   = le_b1[4 * g + r];
            b3_2[r] = as_b1[4 * g + r];
            b5[r]   = 0.0f;
        }
        if (g == 0) { b5[0] = ls_b3[0]; b5[1] = as_b3[0]; b5[2] = as_b3[1]; }
        bLDS[0][lane] = b1;
        bLDS[4][lane] = b3_2;
        bLDS[8][lane] = b5;
    } else if (wave == 1) {
        f4LDS[1][lane] = pack4_rne(
            (m16 < 8) ? le_w2[(k0 + 0) * 8 + m16] : 0.0f,
            (m16 < 8) ? le_w2[(k0 + 1) * 8 + m16] : 0.0f,
            (m16 < 8) ? le_w2[(k0 + 2) * 8 + m16] : 0.0f,
            (m16 < 8) ? le_w2[(k0 + 3) * 8 + m16] : 0.0f);
        f4LDS[5][lane] = pack4_rne(as_w1[(k0+0)*32 + 16 + m16], as_w1[(k0+1)*32 + 16 + m16],
                                   as_w1[(k0+2)*32 + 16 + m16], as_w1[(k0+3)*32 + 16 + m16]);
        f8LDS[0][lane] = cat8(
            pack4_rne(ls_w2[(k0+0)*16 + m16],    ls_w2[(k0+1)*16 + m16],
                      ls_w2[(k0+2)*16 + m16],    ls_w2[(k0+3)*16 + m16]),
            pack4_rne(ls_w2[(16+k0+0)*16 + m16], ls_w2[(16+k0+1)*16 + m16],
                      ls_w2[(16+k0+2)*16 + m16], ls_w2[(16+k0+3)*16 + m16]));
        floatx4 b2, b3_3;
        #pragma unroll
        for (int r = 0; r < 4; ++r) {
            b2[r]   = (4 * g + r < 8) ? le_b2[4 * g + r] : 0.0f;
            b3_3[r] = as_b1[16 + 4 * g + r];
        }
        bLDS[1][lane] = b2;
        bLDS[5][lane] = b3_3;
    } else if (wave == 2) {
        f4LDS[2][lane] = pack4_rne(ls_w1[(k0+0)*32 + m16],      ls_w1[(k0+1)*32 + m16],
                                   ls_w1[(k0+2)*32 + m16],      ls_w1[(k0+3)*32 + m16]);
        f8LDS[1][lane] = cat8(
            pack4_rne(as_w2[(k0+0)*16 + m16],    as_w2[(k0+1)*16 + m16],
                      as_w2[(k0+2)*16 + m16],    as_w2[(k0+3)*16 + m16]),
            pack4_rne(as_w2[(16+k0+0)*16 + m16], as_w2[(16+k0+1)*16 + m16],
                      as_w2[(16+k0+2)*16 + m16], as_w2[(16+k0+3)*16 + m16]));
        floatx4 b3_0, b4ls;
        #pragma unroll
        for (int r = 0; r < 4; ++r) {
            b3_0[r] = ls_b1[4 * g + r];
            b4ls[r] = ls_b2[4 * g + r];
        }
        bLDS[2][lane] = b3_0;
        bLDS[6][lane] = b4ls;
    } else {
        f4LDS[3][lane] = pack4_rne(ls_w1[(k0+0)*32 + 16 + m16], ls_w1[(k0+1)*32 + 16 + m16],
                                   ls_w1[(k0+2)*32 + 16 + m16], ls_w1[(k0+3)*32 + 16 + m16]);
        f8LDS[2][lane] = cat8(
            pack4_rne(
                (m16 == 0) ? ls_w3[k0 + 0] : 0.0f,
                (m16 == 0) ? ls_w3[k0 + 1] : 0.0f,
                (m16 == 0) ? ls_w3[k0 + 2] : 0.0f,
                (m16 == 0) ? ls_w3[k0 + 3] : 0.0f),
            pack4_rne(
                (m16 == 1) ? as_w3[(k0+0)*2] : ((m16 == 2) ? as_w3[(k0+0)*2 + 1] : 0.0f),
                (m16 == 1) ? as_w3[(k0+1)*2] : ((m16 == 2) ? as_w3[(k0+1)*2 + 1] : 0.0f),
                (m16 == 1) ? as_w3[(k0+2)*2] : ((m16 == 2) ? as_w3[(k0+2)*2 + 1] : 0.0f),
                (m16 == 1) ? as_w3[(k0+3)*2] : ((m16 == 2) ? as_w3[(k0+3)*2 + 1] : 0.0f)));
        floatx4 b3_1, b4as;
        #pragma unroll
        for (int r = 0; r < 4; ++r) {
            b3_1[r] = ls_b1[16 + 4 * g + r];
            b4as[r] = as_b2[4 * g + r];
        }
        bLDS[3][lane] = b3_1;
        bLDS[7][lane] = b4as;
        embLDS[lane] = (_Float16)emb[lane];
    }
    __syncthreads();

    // ---- per-lane fragment readback (conflict-light LDS reads) ----
    const half4 a1    = f4LDS[0][lane];
    const half4 a2    = f4LDS[1][lane];
    const half4 a3_0  = f4LDS[2][lane];
    const half4 a3_1  = f4LDS[3][lane];
    const half4 a3_2  = f4LDS[4][lane];
    const half4 a3_3  = f4LDS[5][lane];
    const half8 a4ls  = f8LDS[0][lane];
    const half8 a4as  = f8LDS[1][lane];
    const half8 a5    = f8LDS[2][lane];
    const floatx4 bias1   = bLDS[0][lane];
    const floatx4 bias2   = bLDS[1][lane];
    const floatx4 bias3_0 = bLDS[2][lane];
    const floatx4 bias3_1 = bLDS[3][lane];
    const floatx4 bias3_2 = bLDS[4][lane];
    const floatx4 bias3_3 = bLDS[5][lane];
    const floatx4 bias4ls = bLDS[6][lane];
    const floatx4 bias4as = bLDS[7][lane];
    const floatx4 bias5   = bLDS[8][lane];

    // ---- main loop: 8 tiles per wave, 2 independent chains per iteration ----
    const int tile0 = blockIdx.x * 32 + wave * 8;
    float* __restrict__ out2 = out + BL_TOTAL;

    for (int t = 0; t < 8; t += 2) {
        const int posA = (tile0 + t) * 16 + m16;
        const int posB = posA + 16;

        float ax0 = 0.0f, ax1 = 0.0f, ax2 = 0.0f, ax3 = 0.0f;
        float bx0 = 0.0f, bx1 = 0.0f, bx2 = 0.0f, bx3 = 0.0f;
        if (g == 0) {
            ax0 = lf[posA * 5 + 0]; ax1 = lf[posA * 5 + 1];
            ax2 = lf[posA * 5 + 2]; ax3 = lf[posA * 5 + 3];
            bx0 = lf[posB * 5 + 0]; bx1 = lf[posB * 5 + 1];
            bx2 = lf[posB * 5 + 2]; bx3 = lf[posB * 5 + 3];
        } else if (g == 1) {
            ax0 = lf[posA * 5 + 4];
            bx0 = lf[posB * 5 + 4];
        }
        const int sA = ss[posA];
        const int sB = ss[posB];
        half4 evA = *reinterpret_cast<const half4*>(&embLDS[sA * 8 + (g & 1) * 4]);
        half4 evB = *reinterpret_cast<const half4*>(&embLDS[sB * 8 + (g & 1) * 4]);

        half4 b1A = pack4_rne(ax0, ax1, ax2, ax3);
        half4 b1B = pack4_rne(bx0, bx1, bx2, bx3);

        // L1: 5->16
        floatx4 c1A = MFMA16(a1, b1A, bias1);
        floatx4 c1B = MFMA16(a1, b1B, bias1);
        half4 h1A = relu_pack(c1A);
        half4 h1B = relu_pack(c1B);

        // L2: 16->8
        floatx4 c2A = MFMA16(a2, h1A, bias2);
        floatx4 c2B = MFMA16(a2, h1B, bias2);
        half4 b3A = relu_pack(c2A);
        half4 b3B = relu_pack(c2B);
        if (g >= 2) { b3A = evA; b3B = evB; }

        // L3: 16->64 (both heads' W1 stacked on n)
        floatx4 c30A = MFMA16(a3_0, b3A, bias3_0);
        floatx4 c30B = MFMA16(a3_0, b3B, bias3_0);
        floatx4 c31A = MFMA16(a3_1, b3A, bias3_1);
        floatx4 c31B = MFMA16(a3_1, b3B, bias3_1);
        floatx4 c32A = MFMA16(a3_2, b3A, bias3_2);
        floatx4 c32B = MFMA16(a3_2, b3B, bias3_2);
        floatx4 c33A = MFMA16(a3_3, b3A, bias3_3);
        floatx4 c33B = MFMA16(a3_3, b3B, bias3_3);
        half4 p0A = relu_pack(c30A), p1A = relu_pack(c31A);
        half4 p2A = relu_pack(c32A), p3A = relu_pack(c33A);
        half4 p0B = relu_pack(c30B), p1B = relu_pack(c31B);
        half4 p2B = relu_pack(c32B), p3B = relu_pack(c33B);

        // L4: 32->16 per head, single K=32 MFMA each
        floatx4 clsA = MFMA32(a4ls, cat8(p0A, p1A), bias4ls);
        floatx4 clsB = MFMA32(a4ls, cat8(p0B, p1B), bias4ls);
        floatx4 casA = MFMA32(a4as, cat8(p2A, p3A), bias4as);
        floatx4 casB = MFMA32(a4as, cat8(p2B, p3B), bias4as);
        half4 hlsA = relu_pack(clsA), hasA = relu_pack(casA);
        half4 hlsB = relu_pack(clsB), hasB = relu_pack(casB);

        // L5: 32->3 (hls||has), single K=32 MFMA
        floatx4 c5A = MFMA32(a5, cat8(hlsA, hasA), bias5);
        floatx4 c5B = MFMA32(a5, cat8(hlsB, hasB), bias5);

        // lane group 0 holds n=0 (score), n=1 (av0), n=2 (av1) for position m16
        if (g == 0) {
            out[posA] = c5A[0];
            out[posB] = c5B[0];
            reinterpret_cast<float2*>(out2)[posA] = make_float2(c5A[1], c5A[2]);
            reinterpret_cast<float2*>(out2)[posB] = make_float2(c5B[1], c5B[2]);
        }
    }
}

extern "C" void kernel_launch(void* const* d_in, const int* in_sizes, int n_in,
                              void* d_out, int out_size, void* d_ws, size_t ws_size,
                              hipStream_t stream) {
    const float* lf    = (const float*)d_in[0];
    const int*   ss    = (const int*)  d_in[1];
    const float* le_w1 = (const float*)d_in[2];
    const float* le_b1 = (const float*)d_in[3];
    const float* le_w2 = (const float*)d_in[4];
    const float* le_b2 = (const float*)d_in[5];
    const float* emb   = (const float*)d_in[6];
    const float* ls_w1 = (const float*)d_in[7];
    const float* ls_b1 = (const float*)d_in[8];
    const float* ls_w2 = (const float*)d_in[9];
    const float* ls_b2 = (const float*)d_in[10];
    const float* ls_w3 = (const float*)d_in[11];
    const float* ls_b3 = (const float*)d_in[12];
    const float* as_w1 = (const float*)d_in[13];
    const float* as_b1 = (const float*)d_in[14];
    const float* as_w2 = (const float*)d_in[15];
    const float* as_b2 = (const float*)d_in[16];
    const float* as_w3 = (const float*)d_in[17];
    const float* as_b3 = (const float*)d_in[18];
    float* out = (float*)d_out;

    // 2048 blocks x 4 waves x 8 tiles x 16 positions = 1,048,576
    dqn_mfma<<<2048, 256, 0, stream>>>(
        lf, ss, le_w1, le_b1, le_w2, le_b2, emb,
        ls_w1, ls_b1, ls_w2, ls_b2, ls_w3, ls_b3,
        as_w1, as_b1, as_w2, as_b2, as_w3, as_b3,
        out);
}

// Round 10
// 20.934 us; speedup vs baseline: 1.5452x; 1.2473x over previous
//
#include <hip/hip_runtime.h>

// TrafficNetworkDQN fused forward via fp16 MFMA (gfx950).
//
// All layers computed TRANSPOSED:  Act_out[n, m] = W^T[n,k] @ Act_in[k, m] + b[n]
// with positions m on the MFMA *N* dimension: the C/D fragment layout
// (col = lane&15 = m, row = 4*(lane>>4)+reg = n) equals the K=16 B fragment
// layout (k = 4*(lane>>4)+j); K=32 B frag = in-lane concat of two K=16 C/D
// frags (j>=4 -> k+16). Both HW-verified (R3, R8 passes).
//
// R10: R9 (coop prologue, K=32 L4/L5) +
//  (a) software-pipelined input loads: iteration t prefetches t+2's lf/ss
//      into rotating registers, so the chain head never waits on vmcnt
//      (R7's failure was batch+4-way-unroll register blowup, not the idea);
//  (b) relu in packed f16: cvt_pkrtz then v_pk_max_f16 via
//      __builtin_elementwise_max (compiler-managed, no inline asm),
//      6 -> 4 VALU per transition. max(rtz(x),0) == rtz(max(x,0)).

#define BL_TOTAL (4096 * 256)

typedef _Float16 half4   __attribute__((ext_vector_type(4)));
typedef _Float16 half8   __attribute__((ext_vector_type(8)));
typedef __fp16   fp16x2  __attribute__((ext_vector_type(2)));
typedef float    floatx4 __attribute__((ext_vector_type(4)));

#define MFMA16(A, B, C) __builtin_amdgcn_mfma_f32_16x16x16f16((A), (B), (C), 0, 0, 0)
#define MFMA32(A, B, C) __builtin_amdgcn_mfma_f32_16x16x32_f16((A), (B), (C), 0, 0, 0)

static __device__ __forceinline__ half4 relu_pack(floatx4 c) {
    fp16x2 lo = __builtin_amdgcn_cvt_pkrtz(c[0], c[1]);
    fp16x2 hi = __builtin_amdgcn_cvt_pkrtz(c[2], c[3]);
    half4 h;
    h[0] = (_Float16)lo[0]; h[1] = (_Float16)lo[1];
    h[2] = (_Float16)hi[0]; h[3] = (_Float16)hi[1];
    return __builtin_elementwise_max(h, (half4)(_Float16)0.0f);
}

static __device__ __forceinline__ half4 pack4_rne(float a, float b, float c, float d) {
    half4 r; r[0] = (_Float16)a; r[1] = (_Float16)b; r[2] = (_Float16)c; r[3] = (_Float16)d;
    return r;
}

static __device__ __forceinline__ half8 cat8(half4 x, half4 y) {
    half8 r;
    r[0] = x[0]; r[1] = x[1]; r[2] = x[2]; r[3] = x[3];
    r[4] = y[0]; r[5] = y[1]; r[6] = y[2]; r[7] = y[3];
    return r;
}

struct InPair {
    float a0, a1, a2, a3, b0, b1, b2, b3;
    int sA, sB;
};

static __device__ __forceinline__ InPair load_pair(
    const float* __restrict__ lf, const int* __restrict__ ss,
    int posA, int g)
{
    InPair r;
    r.a0 = r.a1 = r.a2 = r.a3 = 0.0f;
    r.b0 = r.b1 = r.b2 = r.b3 = 0.0f;
    const int posB = posA + 16;
    if (g == 0) {
        r.a0 = lf[posA * 5 + 0]; r.a1 = lf[posA * 5 + 1];
        r.a2 = lf[posA * 5 + 2]; r.a3 = lf[posA * 5 + 3];
        r.b0 = lf[posB * 5 + 0]; r.b1 = lf[posB * 5 + 1];
        r.b2 = lf[posB * 5 + 2]; r.b3 = lf[posB * 5 + 3];
    } else if (g == 1) {
        r.a0 = lf[posA * 5 + 4];
        r.b0 = lf[posB * 5 + 4];
    }
    r.sA = ss[posA];
    r.sB = ss[posB];
    return r;
}

__global__ __launch_bounds__(256, 4) void dqn_mfma(
    const float* __restrict__ lf,    // [BL,5]
    const int*   __restrict__ ss,    // [BL]
    const float* __restrict__ le_w1, const float* __restrict__ le_b1,   // 5x16, 16
    const float* __restrict__ le_w2, const float* __restrict__ le_b2,   // 16x8, 8
    const float* __restrict__ emb,                                      // 8x8
    const float* __restrict__ ls_w1, const float* __restrict__ ls_b1,   // 16x32, 32
    const float* __restrict__ ls_w2, const float* __restrict__ ls_b2,   // 32x16, 16
    const float* __restrict__ ls_w3, const float* __restrict__ ls_b3,   // 16x1, 1
    const float* __restrict__ as_w1, const float* __restrict__ as_b1,   // 16x32, 32
    const float* __restrict__ as_w2, const float* __restrict__ as_b2,   // 32x16, 16
    const float* __restrict__ as_w3, const float* __restrict__ as_b3,   // 16x2, 2
    float* __restrict__ out)         // [BL] scores, then [BL,2] action values
{
    const int lane = threadIdx.x & 63;
    const int wave = threadIdx.x >> 6;
    const int m16  = lane & 15;
    const int g    = lane >> 4;
    const int k0   = g * 4;

    // LDS: 6 half4 frag rows + 3 half8 frag rows + 9 float4 bias rows + emb
    __shared__ half4    f4LDS[6][64];    // a1, a2, a3_0, a3_1, a3_2, a3_3
    __shared__ half8    f8LDS[3][64];    // a4ls, a4as, a5
    __shared__ floatx4  bLDS[9][64];     // bias1,2,3_0,3_1,3_2,3_3,4ls,4as,5
    __shared__ _Float16 embLDS[64];

    // ---- cooperative construction: each wave builds ~1/4 of the rows ----
    if (wave == 0) {
        f4LDS[0][lane] = pack4_rne(
            (k0 + 0 < 5) ? le_w1[(k0 + 0) * 16 + m16] : 0.0f,
            (k0 + 1 < 5) ? le_w1[(k0 + 1) * 16 + m16] : 0.0f,
            (k0 + 2 < 5) ? le_w1[(k0 + 2) * 16 + m16] : 0.0f,
            (k0 + 3 < 5) ? le_w1[(k0 + 3) * 16 + m16] : 0.0f);
        f4LDS[4][lane] = pack4_rne(as_w1[(k0+0)*32 + m16],      as_w1[(k0+1)*32 + m16],
                                   as_w1[(k0+2)*32 + m16],      as_w1[(k0+3)*32 + m16]);
        floatx4 b1, b3_2, b5;
        #pragma unroll
        for (int r = 0; r < 4; ++r) {
            b1[r]   = le_b1[4 * g + r];
            b3_2[r] = as_b1[4 * g + r];
            b5[r]   = 0.0f;
        }
        if (g == 0) { b5[0] = ls_b3[0]; b5[1] = as_b3[0]; b5[2] = as_b3[1]; }
        bLDS[0][lane] = b1;
        bLDS[4][lane] = b3_2;
        bLDS[8][lane] = b5;
    } else if (wave == 1) {
        f4LDS[1][lane] = pack4_rne(
            (m16 < 8) ? le_w2[(k0 + 0) * 8 + m16] : 0.0f,
            (m16 < 8) ? le_w2[(k0 + 1) * 8 + m16] : 0.0f,
            (m16 < 8) ? le_w2[(k0 + 2) * 8 + m16] : 0.0f,
            (m16 < 8) ? le_w2[(k0 + 3) * 8 + m16] : 0.0f);
        f4LDS[5][lane] = pack4_rne(as_w1[(k0+0)*32 + 16 + m16], as_w1[(k0+1)*32 + 16 + m16],
                                   as_w1[(k0+2)*32 + 16 + m16], as_w1[(k0+3)*32 + 16 + m16]);
        f8LDS[0][lane] = cat8(
            pack4_rne(ls_w2[(k0+0)*16 + m16],    ls_w2[(k0+1)*16 + m16],
                      ls_w2[(k0+2)*16 + m16],    ls_w2[(k0+3)*16 + m16]),
            pack4_rne(ls_w2[(16+k0+0)*16 + m16], ls_w2[(16+k0+1)*16 + m16],
                      ls_w2[(16+k0+2)*16 + m16], ls_w2[(16+k0+3)*16 + m16]));
        floatx4 b2, b3_3;
        #pragma unroll
        for (int r = 0; r < 4; ++r) {
            b2[r]   = (4 * g + r < 8) ? le_b2[4 * g + r] : 0.0f;
            b3_3[r] = as_b1[16 + 4 * g + r];
        }
        bLDS[1][lane] = b2;
        bLDS[5][lane] = b3_3;
    } else if (wave == 2) {
        f4LDS[2][lane] = pack4_rne(ls_w1[(k0+0)*32 + m16],      ls_w1[(k0+1)*32 + m16],
                                   ls_w1[(k0+2)*32 + m16],      ls_w1[(k0+3)*32 + m16]);
        f8LDS[1][lane] = cat8(
            pack4_rne(as_w2[(k0+0)*16 + m16],    as_w2[(k0+1)*16 + m16],
                      as_w2[(k0+2)*16 + m16],    as_w2[(k0+3)*16 + m16]),
            pack4_rne(as_w2[(16+k0+0)*16 + m16], as_w2[(16+k0+1)*16 + m16],
                      as_w2[(16+k0+2)*16 + m16], as_w2[(16+k0+3)*16 + m16]));
        floatx4 b3_0, b4ls;
        #pragma unroll
        for (int r = 0; r < 4; ++r) {
            b3_0[r] = ls_b1[4 * g + r];
            b4ls[r] = ls_b2[4 * g + r];
        }
        bLDS[2][lane] = b3_0;
        bLDS[6][lane] = b4ls;
    } else {
        f4LDS[3][lane] = pack4_rne(ls_w1[(k0+0)*32 + 16 + m16], ls_w1[(k0+1)*32 + 16 + m16],
                                   ls_w1[(k0+2)*32 + 16 + m16], ls_w1[(k0+3)*32 + 16 + m16]);
        f8LDS[2][lane] = cat8(
            pack4_rne(
                (m16 == 0) ? ls_w3[k0 + 0] : 0.0f,
                (m16 == 0) ? ls_w3[k0 + 1] : 0.0f,
                (m16 == 0) ? ls_w3[k0 + 2] : 0.0f,
                (m16 == 0) ? ls_w3[k0 + 3] : 0.0f),
            pack4_rne(
                (m16 == 1) ? as_w3[(k0+0)*2] : ((m16 == 2) ? as_w3[(k0+0)*2 + 1] : 0.0f),
                (m16 == 1) ? as_w3[(k0+1)*2] : ((m16 == 2) ? as_w3[(k0+1)*2 + 1] : 0.0f),
                (m16 == 1) ? as_w3[(k0+2)*2] : ((m16 == 2) ? as_w3[(k0+2)*2 + 1] : 0.0f),
                (m16 == 1) ? as_w3[(k0+3)*2] : ((m16 == 2) ? as_w3[(k0+3)*2 + 1] : 0.0f)));
        floatx4 b3_1, b4as;
        #pragma unroll
        for (int r = 0; r < 4; ++r) {
            b3_1[r] = ls_b1[16 + 4 * g + r];
            b4as[r] = as_b2[4 * g + r];
        }
        bLDS[3][lane] = b3_1;
        bLDS[7][lane] = b4as;
        embLDS[lane] = (_Float16)emb[lane];
    }
    __syncthreads();

    // ---- per-lane fragment readback (conflict-light LDS reads) ----
    const half4 a1    = f4LDS[0][lane];
    const half4 a2    = f4LDS[1][lane];
    const half4 a3_0  = f4LDS[2][lane];
    const half4 a3_1  = f4LDS[3][lane];
    const half4 a3_2  = f4LDS[4][lane];
    const half4 a3_3  = f4LDS[5][lane];
    const half8 a4ls  = f8LDS[0][lane];
    const half8 a4as  = f8LDS[1][lane];
    const half8 a5    = f8LDS[2][lane];
    const floatx4 bias1   = bLDS[0][lane];
    const floatx4 bias2   = bLDS[1][lane];
    const floatx4 bias3_0 = bLDS[2][lane];
    const floatx4 bias3_1 = bLDS[3][lane];
    const floatx4 bias3_2 = bLDS[4][lane];
    const floatx4 bias3_3 = bLDS[5][lane];
    const floatx4 bias4ls = bLDS[6][lane];
    const floatx4 bias4as = bLDS[7][lane];
    const floatx4 bias5   = bLDS[8][lane];

    // ---- main loop: 8 tiles per wave, 2 chains/iter, inputs pipelined ----
    const int tile0 = blockIdx.x * 32 + wave * 8;
    float* __restrict__ out2 = out + BL_TOTAL;

    InPair cur = load_pair(lf, ss, tile0 * 16 + m16, g);

    for (int t = 0; t < 8; t += 2) {
        // prefetch next iteration's inputs (issued before the chain starts)
        InPair nxt = {};
        if (t + 2 < 8)
            nxt = load_pair(lf, ss, (tile0 + t + 2) * 16 + m16, g);

        const int posA = (tile0 + t) * 16 + m16;
        const int posB = posA + 16;

        half4 evA = *reinterpret_cast<const half4*>(&embLDS[cur.sA * 8 + (g & 1) * 4]);
        half4 evB = *reinterpret_cast<const half4*>(&embLDS[cur.sB * 8 + (g & 1) * 4]);

        half4 b1A = pack4_rne(cur.a0, cur.a1, cur.a2, cur.a3);
        half4 b1B = pack4_rne(cur.b0, cur.b1, cur.b2, cur.b3);

        // L1: 5->16
        floatx4 c1A = MFMA16(a1, b1A, bias1);
        floatx4 c1B = MFMA16(a1, b1B, bias1);
        half4 h1A = relu_pack(c1A);
        half4 h1B = relu_pack(c1B);

        // L2: 16->8
        floatx4 c2A = MFMA16(a2, h1A, bias2);
        floatx4 c2B = MFMA16(a2, h1B, bias2);
        half4 b3A = relu_pack(c2A);
        half4 b3B = relu_pack(c2B);
        if (g >= 2) { b3A = evA; b3B = evB; }

        // L3: 16->64 (both heads' W1 stacked on n)
        floatx4 c30A = MFMA16(a3_0, b3A, bias3_0);
        floatx4 c30B = MFMA16(a3_0, b3B, bias3_0);
        floatx4 c31A = MFMA16(a3_1, b3A, bias3_1);
        floatx4 c31B = MFMA16(a3_1, b3B, bias3_1);
        floatx4 c32A = MFMA16(a3_2, b3A, bias3_2);
        floatx4 c32B = MFMA16(a3_2, b3B, bias3_2);
        floatx4 c33A = MFMA16(a3_3, b3A, bias3_3);
        floatx4 c33B = MFMA16(a3_3, b3B, bias3_3);
        half4 p0A = relu_pack(c30A), p1A = relu_pack(c31A);
        half4 p2A = relu_pack(c32A), p3A = relu_pack(c33A);
        half4 p0B = relu_pack(c30B), p1B = relu_pack(c31B);
        half4 p2B = relu_pack(c32B), p3B = relu_pack(c33B);

        // L4: 32->16 per head, single K=32 MFMA each
        floatx4 clsA = MFMA32(a4ls, cat8(p0A, p1A), bias4ls);
        floatx4 clsB = MFMA32(a4ls, cat8(p0B, p1B), bias4ls);
        floatx4 casA = MFMA32(a4as, cat8(p2A, p3A), bias4as);
        floatx4 casB = MFMA32(a4as, cat8(p2B, p3B), bias4as);
        half4 hlsA = relu_pack(clsA), hasA = relu_pack(casA);
        half4 hlsB = relu_pack(clsB), hasB = relu_pack(casB);

        // L5: 32->3 (hls||has), single K=32 MFMA
        floatx4 c5A = MFMA32(a5, cat8(hlsA, hasA), bias5);
        floatx4 c5B = MFMA32(a5, cat8(hlsB, hasB), bias5);

        // lane group 0 holds n=0 (score), n=1 (av0), n=2 (av1) for position m16
        if (g == 0) {
            out[posA] = c5A[0];
            out[posB] = c5B[0];
            reinterpret_cast<float2*>(out2)[posA] = make_float2(c5A[1], c5A[2]);
            reinterpret_cast<float2*>(out2)[posB] = make_float2(c5B[1], c5B[2]);
        }

        cur = nxt;
    }
}

extern "C" void kernel_launch(void* const* d_in, const int* in_sizes, int n_in,
                              void* d_out, int out_size, void* d_ws, size_t ws_size,
                              hipStream_t stream) {
    const float* lf    = (const float*)d_in[0];
    const int*   ss    = (const int*)  d_in[1];
    const float* le_w1 = (const float*)d_in[2];
    const float* le_b1 = (const float*)d_in[3];
    const float* le_w2 = (const float*)d_in[4];
    const float* le_b2 = (const float*)d_in[5];
    const float* emb   = (const float*)d_in[6];
    const float* ls_w1 = (const float*)d_in[7];
    const float* ls_b1 = (const float*)d_in[8];
    const float* ls_w2 = (const float*)d_in[9];
    const float* ls_b2 = (const float*)d_in[10];
    const float* ls_w3 = (const float*)d_in[11];
    const float* ls_b3 = (const float*)d_in[12];
    const float* as_w1 = (const float*)d_in[13];
    const float* as_b1 = (const float*)d_in[14];
    const float* as_w2 = (const float*)d_in[15];
    const float* as_b2 = (const float*)d_in[16];
    const float* as_w3 = (const float*)d_in[17];
    const float* as_b3 = (const float*)d_in[18];
    float* out = (float*)d_out;

    // 2048 blocks x 4 waves x 8 tiles x 16 positions = 1,048,576
    dqn_mfma<<<2048, 256, 0, stream>>>(
        lf, ss, le_w1, le_b1, le_w2, le_b2, emb,
        ls_w1, ls_b1, ls_w2, ls_b2, ls_w3, ls_b3,
        as_w1, as_b1, as_w2, as_b2, as_w3, as_b3,
        out);
}

// Round 11
// 19.960 us; speedup vs baseline: 1.6206x; 1.0488x over previous
//
#include <hip/hip_runtime.h>

// TrafficNetworkDQN fused forward via fp16 MFMA (gfx950).
//
// All layers computed TRANSPOSED:  Act_out[n, m] = W^T[n,k] @ Act_in[k, m] + b[n]
// with positions m on the MFMA *N* dimension: the C/D fragment layout
// (col = lane&15 = m, row = 4*(lane>>4)+reg = n) equals the K=16 B fragment
// layout (k = 4*(lane>>4)+j); K=32 B frag = in-lane concat of two K=16 C/D
// frags (j>=4 -> k+16). Both HW-verified (R3, R8 passes).
//
// R11: deeper input pipelining (the confirmed lever from R10's +20%):
//  - iterations 0 and 1's lf/ss loads issue BEFORE the cooperative LDS
//    prologue (hidden behind ~1-2k cyc of construction + barrier);
//  - in-loop prefetch distance 2 (issue t+4 at top of t), unrolled so the
//    3-stage rotation is pure SSA (no dynamic indexing -> no scratch);
//  - input pack via cvt_pkrtz (2 VALU vs 6).

#define BL_TOTAL (4096 * 256)

typedef _Float16 half4   __attribute__((ext_vector_type(4)));
typedef _Float16 half8   __attribute__((ext_vector_type(8)));
typedef __fp16   fp16x2  __attribute__((ext_vector_type(2)));
typedef float    floatx4 __attribute__((ext_vector_type(4)));

#define MFMA16(A, B, C) __builtin_amdgcn_mfma_f32_16x16x16f16((A), (B), (C), 0, 0, 0)
#define MFMA32(A, B, C) __builtin_amdgcn_mfma_f32_16x16x32_f16((A), (B), (C), 0, 0, 0)

static __device__ __forceinline__ half4 relu_pack(floatx4 c) {
    fp16x2 lo = __builtin_amdgcn_cvt_pkrtz(c[0], c[1]);
    fp16x2 hi = __builtin_amdgcn_cvt_pkrtz(c[2], c[3]);
    half4 h;
    h[0] = (_Float16)lo[0]; h[1] = (_Float16)lo[1];
    h[2] = (_Float16)hi[0]; h[3] = (_Float16)hi[1];
    return __builtin_elementwise_max(h, (half4)(_Float16)0.0f);
}

static __device__ __forceinline__ half4 pack_rtz(float a, float b, float c, float d) {
    fp16x2 lo = __builtin_amdgcn_cvt_pkrtz(a, b);
    fp16x2 hi = __builtin_amdgcn_cvt_pkrtz(c, d);
    half4 r;
    r[0] = (_Float16)lo[0]; r[1] = (_Float16)lo[1];
    r[2] = (_Float16)hi[0]; r[3] = (_Float16)hi[1];
    return r;
}

static __device__ __forceinline__ half4 pack4_rne(float a, float b, float c, float d) {
    half4 r; r[0] = (_Float16)a; r[1] = (_Float16)b; r[2] = (_Float16)c; r[3] = (_Float16)d;
    return r;
}

static __device__ __forceinline__ half8 cat8(half4 x, half4 y) {
    half8 r;
    r[0] = x[0]; r[1] = x[1]; r[2] = x[2]; r[3] = x[3];
    r[4] = y[0]; r[5] = y[1]; r[6] = y[2]; r[7] = y[3];
    return r;
}

struct InPair {
    float a0, a1, a2, a3, b0, b1, b2, b3;
    int sA, sB;
};

static __device__ __forceinline__ InPair load_pair(
    const float* __restrict__ lf, const int* __restrict__ ss,
    int posA, int g)
{
    InPair r;
    r.a0 = r.a1 = r.a2 = r.a3 = 0.0f;
    r.b0 = r.b1 = r.b2 = r.b3 = 0.0f;
    const int posB = posA + 16;
    if (g == 0) {
        r.a0 = lf[posA * 5 + 0]; r.a1 = lf[posA * 5 + 1];
        r.a2 = lf[posA * 5 + 2]; r.a3 = lf[posA * 5 + 3];
        r.b0 = lf[posB * 5 + 0]; r.b1 = lf[posB * 5 + 1];
        r.b2 = lf[posB * 5 + 2]; r.b3 = lf[posB * 5 + 3];
    } else if (g == 1) {
        r.a0 = lf[posA * 5 + 4];
        r.b0 = lf[posB * 5 + 4];
    }
    r.sA = ss[posA];
    r.sB = ss[posB];
    return r;
}

__global__ __launch_bounds__(256, 4) void dqn_mfma(
    const float* __restrict__ lf,    // [BL,5]
    const int*   __restrict__ ss,    // [BL]
    const float* __restrict__ le_w1, const float* __restrict__ le_b1,   // 5x16, 16
    const float* __restrict__ le_w2, const float* __restrict__ le_b2,   // 16x8, 8
    const float* __restrict__ emb,                                      // 8x8
    const float* __restrict__ ls_w1, const float* __restrict__ ls_b1,   // 16x32, 32
    const float* __restrict__ ls_w2, const float* __restrict__ ls_b2,   // 32x16, 16
    const float* __restrict__ ls_w3, const float* __restrict__ ls_b3,   // 16x1, 1
    const float* __restrict__ as_w1, const float* __restrict__ as_b1,   // 16x32, 32
    const float* __restrict__ as_w2, const float* __restrict__ as_b2,   // 32x16, 16
    const float* __restrict__ as_w3, const float* __restrict__ as_b3,   // 16x2, 2
    float* __restrict__ out)         // [BL] scores, then [BL,2] action values
{
    const int lane = threadIdx.x & 63;
    const int wave = threadIdx.x >> 6;
    const int m16  = lane & 15;
    const int g    = lane >> 4;
    const int k0   = g * 4;

    const int tile0 = blockIdx.x * 32 + wave * 8;

    // ---- pre-prologue prefetch: iterations 0 and 1 (hidden under prologue) ----
    InPair p0 = load_pair(lf, ss, (tile0 + 0) * 16 + m16, g);
    InPair p1 = load_pair(lf, ss, (tile0 + 2) * 16 + m16, g);

    // LDS: 6 half4 frag rows + 3 half8 frag rows + 9 float4 bias rows + emb
    __shared__ half4    f4LDS[6][64];    // a1, a2, a3_0, a3_1, a3_2, a3_3
    __shared__ half8    f8LDS[3][64];    // a4ls, a4as, a5
    __shared__ floatx4  bLDS[9][64];     // bias1,2,3_0,3_1,3_2,3_3,4ls,4as,5
    __shared__ _Float16 embLDS[64];

    // ---- cooperative construction: each wave builds ~1/4 of the rows ----
    if (wave == 0) {
        f4LDS[0][lane] = pack4_rne(
            (k0 + 0 < 5) ? le_w1[(k0 + 0) * 16 + m16] : 0.0f,
            (k0 + 1 < 5) ? le_w1[(k0 + 1) * 16 + m16] : 0.0f,
            (k0 + 2 < 5) ? le_w1[(k0 + 2) * 16 + m16] : 0.0f,
            (k0 + 3 < 5) ? le_w1[(k0 + 3) * 16 + m16] : 0.0f);
        f4LDS[4][lane] = pack4_rne(as_w1[(k0+0)*32 + m16],      as_w1[(k0+1)*32 + m16],
                                   as_w1[(k0+2)*32 + m16],      as_w1[(k0+3)*32 + m16]);
        floatx4 b1, b3_2, b5;
        #pragma unroll
        for (int r = 0; r < 4; ++r) {
            b1[r]   = le_b1[4 * g + r];
            b3_2[r] = as_b1[4 * g + r];
            b5[r]   = 0.0f;
        }
        if (g == 0) { b5[0] = ls_b3[0]; b5[1] = as_b3[0]; b5[2] = as_b3[1]; }
        bLDS[0][lane] = b1;
        bLDS[4][lane] = b3_2;
        bLDS[8][lane] = b5;
    } else if (wave == 1) {
        f4LDS[1][lane] = pack4_rne(
            (m16 < 8) ? le_w2[(k0 + 0) * 8 + m16] : 0.0f,
            (m16 < 8) ? le_w2[(k0 + 1) * 8 + m16] : 0.0f,
            (m16 < 8) ? le_w2[(k0 + 2) * 8 + m16] : 0.0f,
            (m16 < 8) ? le_w2[(k0 + 3) * 8 + m16] : 0.0f);
        f4LDS[5][lane] = pack4_rne(as_w1[(k0+0)*32 + 16 + m16], as_w1[(k0+1)*32 + 16 + m16],
                                   as_w1[(k0+2)*32 + 16 + m16], as_w1[(k0+3)*32 + 16 + m16]);
        f8LDS[0][lane] = cat8(
            pack4_rne(ls_w2[(k0+0)*16 + m16],    ls_w2[(k0+1)*16 + m16],
                      ls_w2[(k0+2)*16 + m16],    ls_w2[(k0+3)*16 + m16]),
            pack4_rne(ls_w2[(16+k0+0)*16 + m16], ls_w2[(16+k0+1)*16 + m16],
                      ls_w2[(16+k0+2)*16 + m16], ls_w2[(16+k0+3)*16 + m16]));
        floatx4 b2, b3_3;
        #pragma unroll
        for (int r = 0; r < 4; ++r) {
            b2[r]   = (4 * g + r < 8) ? le_b2[4 * g + r] : 0.0f;
            b3_3[r] = as_b1[16 + 4 * g + r];
        }
        bLDS[1][lane] = b2;
        bLDS[5][lane] = b3_3;
    } else if (wave == 2) {
        f4LDS[2][lane] = pack4_rne(ls_w1[(k0+0)*32 + m16],      ls_w1[(k0+1)*32 + m16],
                                   ls_w1[(k0+2)*32 + m16],      ls_w1[(k0+3)*32 + m16]);
        f8LDS[1][lane] = cat8(
            pack4_rne(as_w2[(k0+0)*16 + m16],    as_w2[(k0+1)*16 + m16],
                      as_w2[(k0+2)*16 + m16],    as_w2[(k0+3)*16 + m16]),
            pack4_rne(as_w2[(16+k0+0)*16 + m16], as_w2[(16+k0+1)*16 + m16],
                      as_w2[(16+k0+2)*16 + m16], as_w2[(16+k0+3)*16 + m16]));
        floatx4 b3_0, b4ls;
        #pragma unroll
        for (int r = 0; r < 4; ++r) {
            b3_0[r] = ls_b1[4 * g + r];
            b4ls[r] = ls_b2[4 * g + r];
        }
        bLDS[2][lane] = b3_0;
        bLDS[6][lane] = b4ls;
    } else {
        f4LDS[3][lane] = pack4_rne(ls_w1[(k0+0)*32 + 16 + m16], ls_w1[(k0+1)*32 + 16 + m16],
                                   ls_w1[(k0+2)*32 + 16 + m16], ls_w1[(k0+3)*32 + 16 + m16]);
        f8LDS[2][lane] = cat8(
            pack4_rne(
                (m16 == 0) ? ls_w3[k0 + 0] : 0.0f,
                (m16 == 0) ? ls_w3[k0 + 1] : 0.0f,
                (m16 == 0) ? ls_w3[k0 + 2] : 0.0f,
                (m16 == 0) ? ls_w3[k0 + 3] : 0.0f),
            pack4_rne(
                (m16 == 1) ? as_w3[(k0+0)*2] : ((m16 == 2) ? as_w3[(k0+0)*2 + 1] : 0.0f),
                (m16 == 1) ? as_w3[(k0+1)*2] : ((m16 == 2) ? as_w3[(k0+1)*2 + 1] : 0.0f),
                (m16 == 1) ? as_w3[(k0+2)*2] : ((m16 == 2) ? as_w3[(k0+2)*2 + 1] : 0.0f),
                (m16 == 1) ? as_w3[(k0+3)*2] : ((m16 == 2) ? as_w3[(k0+3)*2 + 1] : 0.0f)));
        floatx4 b3_1, b4as;
        #pragma unroll
        for (int r = 0; r < 4; ++r) {
            b3_1[r] = ls_b1[16 + 4 * g + r];
            b4as[r] = as_b2[4 * g + r];
        }
        bLDS[3][lane] = b3_1;
        bLDS[7][lane] = b4as;
        embLDS[lane] = (_Float16)emb[lane];
    }
    __syncthreads();

    // ---- per-lane fragment readback (conflict-light LDS reads) ----
    const half4 a1    = f4LDS[0][lane];
    const half4 a2    = f4LDS[1][lane];
    const half4 a3_0  = f4LDS[2][lane];
    const half4 a3_1  = f4LDS[3][lane];
    const half4 a3_2  = f4LDS[4][lane];
    const half4 a3_3  = f4LDS[5][lane];
    const half8 a4ls  = f8LDS[0][lane];
    const half8 a4as  = f8LDS[1][lane];
    const half8 a5    = f8LDS[2][lane];
    const floatx4 bias1   = bLDS[0][lane];
    const floatx4 bias2   = bLDS[1][lane];
    const floatx4 bias3_0 = bLDS[2][lane];
    const floatx4 bias3_1 = bLDS[3][lane];
    const floatx4 bias3_2 = bLDS[4][lane];
    const floatx4 bias3_3 = bLDS[5][lane];
    const floatx4 bias4ls = bLDS[6][lane];
    const floatx4 bias4as = bLDS[7][lane];
    const floatx4 bias5   = bLDS[8][lane];

    // ---- main loop: 8 tiles/wave, 2 chains/iter, depth-2 input pipeline ----
    float* __restrict__ out2 = out + BL_TOTAL;

    #pragma unroll
    for (int t = 0; t < 8; t += 2) {
        // prefetch two iterations ahead
        InPair p2 = {};
        if (t + 4 < 8)
            p2 = load_pair(lf, ss, (tile0 + t + 4) * 16 + m16, g);

        const int posA = (tile0 + t) * 16 + m16;
        const int posB = posA + 16;

        half4 evA = *reinterpret_cast<const half4*>(&embLDS[p0.sA * 8 + (g & 1) * 4]);
        half4 evB = *reinterpret_cast<const half4*>(&embLDS[p0.sB * 8 + (g & 1) * 4]);

        half4 b1A = pack_rtz(p0.a0, p0.a1, p0.a2, p0.a3);
        half4 b1B = pack_rtz(p0.b0, p0.b1, p0.b2, p0.b3);

        // L1: 5->16
        floatx4 c1A = MFMA16(a1, b1A, bias1);
        floatx4 c1B = MFMA16(a1, b1B, bias1);
        half4 h1A = relu_pack(c1A);
        half4 h1B = relu_pack(c1B);

        // L2: 16->8
        floatx4 c2A = MFMA16(a2, h1A, bias2);
        floatx4 c2B = MFMA16(a2, h1B, bias2);
        half4 b3A = relu_pack(c2A);
        half4 b3B = relu_pack(c2B);
        if (g >= 2) { b3A = evA; b3B = evB; }

        // L3: 16->64 (both heads' W1 stacked on n)
        floatx4 c30A = MFMA16(a3_0, b3A, bias3_0);
        floatx4 c30B = MFMA16(a3_0, b3B, bias3_0);
        floatx4 c31A = MFMA16(a3_1, b3A, bias3_1);
        floatx4 c31B = MFMA16(a3_1, b3B, bias3_1);
        floatx4 c32A = MFMA16(a3_2, b3A, bias3_2);
        floatx4 c32B = MFMA16(a3_2, b3B, bias3_2);
        floatx4 c33A = MFMA16(a3_3, b3A, bias3_3);
        floatx4 c33B = MFMA16(a3_3, b3B, bias3_3);
        half4 p0A = relu_pack(c30A), p1A = relu_pack(c31A);
        half4 p2A = relu_pack(c32A), p3A = relu_pack(c33A);
        half4 p0B = relu_pack(c30B), p1B = relu_pack(c31B);
        half4 p2B = relu_pack(c32B), p3B = relu_pack(c33B);

        // L4: 32->16 per head, single K=32 MFMA each
        floatx4 clsA = MFMA32(a4ls, cat8(p0A, p1A), bias4ls);
        floatx4 clsB = MFMA32(a4ls, cat8(p0B, p1B), bias4ls);
        floatx4 casA = MFMA32(a4as, cat8(p2A, p3A), bias4as);
        floatx4 casB = MFMA32(a4as, cat8(p2B, p3B), bias4as);
        half4 hlsA = relu_pack(clsA), hasA = relu_pack(casA);
        half4 hlsB = relu_pack(clsB), hasB = relu_pack(casB);

        // L5: 32->3 (hls||has), single K=32 MFMA
        floatx4 c5A = MFMA32(a5, cat8(hlsA, hasA), bias5);
        floatx4 c5B = MFMA32(a5, cat8(hlsB, hasB), bias5);

        // lane group 0 holds n=0 (score), n=1 (av0), n=2 (av1) for position m16
        if (g == 0) {
            out[posA] = c5A[0];
            out[posB] = c5B[0];
            reinterpret_cast<float2*>(out2)[posA] = make_float2(c5A[1], c5A[2]);
            reinterpret_cast<float2*>(out2)[posB] = make_float2(c5B[1], c5B[2]);
        }

        p0 = p1;
        p1 = p2;
    }
}

extern "C" void kernel_launch(void* const* d_in, const int* in_sizes, int n_in,
                              void* d_out, int out_size, void* d_ws, size_t ws_size,
                              hipStream_t stream) {
    const float* lf    = (const float*)d_in[0];
    const int*   ss    = (const int*)  d_in[1];
    const float* le_w1 = (const float*)d_in[2];
    const float* le_b1 = (const float*)d_in[3];
    const float* le_w2 = (const float*)d_in[4];
    const float* le_b2 = (const float*)d_in[5];
    const float* emb   = (const float*)d_in[6];
    const float* ls_w1 = (const float*)d_in[7];
    const float* ls_b1 = (const float*)d_in[8];
    const float* ls_w2 = (const float*)d_in[9];
    const float* ls_b2 = (const float*)d_in[10];
    const float* ls_w3 = (const float*)d_in[11];
    const float* ls_b3 = (const float*)d_in[12];
    const float* as_w1 = (const float*)d_in[13];
    const float* as_b1 = (const float*)d_in[14];
    const float* as_w2 = (const float*)d_in[15];
    const float* as_b2 = (const float*)d_in[16];
    const float* as_w3 = (const float*)d_in[17];
    const float* as_b3 = (const float*)d_in[18];
    float* out = (float*)d_out;

    // 2048 blocks x 4 waves x 8 tiles x 16 positions = 1,048,576
    dqn_mfma<<<2048, 256, 0, stream>>>(
        lf, ss, le_w1, le_b1, le_w2, le_b2, emb,
        ls_w1, ls_b1, ls_w2, ls_b2, ls_w3, ls_b3,
        as_w1, as_b1, as_w2, as_b2, as_w3, as_b3,
        out);
}